// Round 8
// baseline (728.065 us; speedup 1.0000x reference)
//
#include <hip/hip_runtime.h>

// ct_layer round 15: DPP o-shift — LDS-read-BW debottleneck of the Q16 core.
//   R14 audit: 60 ds_read_b128/wave/cb (3o x 2jh x 10r) = 480KB/CU/cb over a
//   128B/cyc LDS port (>=3750cyc) vs 2800cyc MFMA -> LDS-bound, matching
//   MfmaUtil 56%. Fix: read 18 rows ONCE per cb; derive o=1,2 fragments via
//   v_mov_b32_dpp row_shl:1 (frag[wl] <- frag[wl+1], VALU pipe) + 4-lane
//   masked patch read for wl=15 (halo col 16+o). LDS ops 60->18 heavy + 36
//   tiny; weights still once per (o,p). Bit-identical numerics (same (cb,o,p)
//   accumulation order, DPP moves exact bytes).
//   Everything else identical to R14 (fused main, epi_c1, Q16b c2, aux).

typedef _Float16 f16x8 __attribute__((ext_vector_type(8)));
typedef _Float16 f16x4v __attribute__((ext_vector_type(4)));
typedef float f32x4 __attribute__((ext_vector_type(4)));

#define HP 98
#define WP 98
#define KTOT 2304
#define WSET (256*KTOT)                // 589824 elems per weight set
#define XPAD_E ((size_t)8*HP*WP*256)
#define UVP_E  ((size_t)8*98*256)      // u_pad/v_pad f32 (atomic targets)
#define UV2_E  ((size_t)3*8*96*256)    // u2/v2 f32 [case][b][pos][co]
#define WUV_SET 196608                 // 256co * 768k per (t,case)

// XCD-aware block swizzle (requires nwg % 8 == 0).
__device__ __forceinline__ int xcd_swz(int bid, int nwg)
{
  return (bid & 7) * (nwg >> 3) + (bid >> 3);
}

#define BUF_Q 24576
#define SMEM_Q 49152

// lane shift within 16-lane rows: dst[wl] = src[wl+1] (row_shl:1, bound->0)
__device__ __forceinline__ f16x8 dpp_shl1(f16x8 v)
{
  union U { f16x8 h; int d[4]; } a, r;
  a.h = v;
#pragma unroll
  for (int k = 0; k < 4; ++k)
    r.d[k] = __builtin_amdgcn_update_dpp(0, a.d[k], 0x101, 0xf, 0xf, true);
  return r.h;
}

// Shared per-cb compute: 18-row read + DPP o-shift + 288 MFMA.
// S: tap = (S==0) ? p*3+o : o*3+p  (weight layout tap = dh*3+dw).
template<int S>
__device__ __forceinline__ void conv_cb_compute(const _Float16* __restrict__ B,
                                                const _Float16* __restrict__ A,
                                                int wl, int quad, f32x4 acc[2][16])
{
  f16x8 cache[18];
#pragma unroll
  for (int r = 0; r < 18; ++r)
    cache[r] = *(const f16x8*)(B + (r * 18 + wl) * 32 + quad * 8);
#pragma unroll
  for (int o = 0; o < 3; ++o) {
    if (o) {
#pragma unroll
      for (int r = 0; r < 18; ++r) cache[r] = dpp_shl1(cache[r]);
      if (wl == 15) {
#pragma unroll
        for (int r = 0; r < 18; ++r)
          cache[r] = *(const f16x8*)(B + (r * 18 + 15 + o) * 32 + quad * 8);
      }
    }
#pragma unroll
    for (int p = 0; p < 3; ++p) {
      const int tap = (S == 0) ? p * 3 + o : o * 3 + p;
      const f16x8 af0 = *(const f16x8*)(A + tap * 8192);
      const f16x8 af1 = *(const f16x8*)(A + tap * 8192 + 512);
#pragma unroll
      for (int j = 0; j < 16; ++j) {
        acc[0][j] = __builtin_amdgcn_mfma_f32_16x16x32_f16(af0, cache[j + p], acc[0][j], 0, 0, 0);
        acc[1][j] = __builtin_amdgcn_mfma_f32_16x16x32_f16(af1, cache[j + p], acc[1][j], 0, 0, 0);
      }
    }
  }
}

// ---------------- Q16 conv core (4-wave): 32co x 256n per wave ------------
struct CtxQ {
  unsigned goff[6];
  unsigned lds_stage;
  unsigned aoff;
  int wl, quad, wv;
  int b, h0, w0;
};

template<int SW>
__device__ __forceinline__ CtxQ make_ctxQ(int spatial, int ch)
{
  CtxQ c;
  c.b = spatial / 36;
  const int tt = spatial - c.b * 36;
  const int ht = tt / 6, wt = tt - ht * 6;
  c.h0 = ht * 16; c.w0 = wt * 16;
  const int tid = threadIdx.x, lane = tid & 63;
  c.wv = tid >> 6;
  c.quad = lane >> 4; c.wl = lane & 15;
  c.aoff = (unsigned)((ch * 8 + c.wv * 2) * 512 + c.wl * 32 + c.quad * 8);
  const unsigned base_hw = (unsigned)(c.b * HP + c.h0) * WP + c.w0;
#pragma unroll
  for (int t = 0; t < 6; ++t) {
    int s = (c.wv * 6 + t) * 16 + (lane >> 2);   // 0..383; 324..383 dummy
    if (s > 323) s = 323;
    const int x = s / 18, y = s - x * 18;
    const int wh = SW ? y : x, ww = SW ? x : y;
    c.goff[t] = (base_hw + (unsigned)(wh * WP + ww)) * 256u + (lane & 3) * 8u;
  }
  c.lds_stage = (unsigned)(c.wv * 6) * 1024u + (unsigned)lane * 16u;
  return c;
}

__device__ __forceinline__ void stage_cbQ(const _Float16* __restrict__ src,
                                          char* sbuf, const CtxQ& c, int buf, int cb)
{
  char* l0 = sbuf + buf * BUF_Q + c.lds_stage;
#pragma unroll
  for (int t = 0; t < 6; ++t) {
    const _Float16* g = src + c.goff[t] + cb * 32;
    __builtin_amdgcn_global_load_lds(
        (const __attribute__((address_space(1))) void*)g,
        (__attribute__((address_space(3))) void*)(l0 + t * 1024), 16, 0, 0);
  }
}

template<int S>
__device__ __forceinline__ void conv_accumQ(const _Float16* __restrict__ src,
                                            const _Float16* __restrict__ wkb,
                                            char* sbuf, const CtxQ& c, f32x4 acc[2][16])
{
  const _Float16* A0 = wkb + c.aoff;
  stage_cbQ(src, sbuf, c, 0, 0);
#pragma unroll 1
  for (int cb = 0; cb < 8; ++cb) {
    __syncthreads();
    if (cb < 7) stage_cbQ(src, sbuf, c, (cb + 1) & 1, cb + 1);
    conv_cb_compute<S>((const _Float16*)(sbuf + (cb & 1) * BUF_Q),
                       A0 + cb * (9 * 8192), c.wl, c.quad, acc);
  }
  __syncthreads();
}

#define ZERO_ACCQ(acc) \
  _Pragma("unroll") for (int i = 0; i < 2; ++i) \
  _Pragma("unroll") for (int j = 0; j < 16; ++j) acc[i][j] = (f32x4){0.f,0.f,0.f,0.f};

// ---------------- Q16b conv core (2-wave, for c2): 64co x 256n per block --
struct CtxB {
  unsigned goff[6];
  unsigned mask;                       // bits 0-5: y>=12 (delta sel); 6-11: dummy
  unsigned lds_stage;
  unsigned aoff;
  int wl, quad, wv;
  int b, h0, w0;
};

template<int SW>
__device__ __forceinline__ CtxB make_ctxB(int spatial, int ch)
{
  CtxB c;
  c.b = spatial / 36;
  const int tt = spatial - c.b * 36;
  const int ht = tt / 6, wt = tt - ht * 6;
  c.h0 = ht * 16; c.w0 = wt * 16;
  const int tid = threadIdx.x, lane = tid & 63;
  c.wv = tid >> 6;                     // 0..1
  c.quad = lane >> 4; c.wl = lane & 15;
  c.aoff = (unsigned)((ch * 4 + c.wv * 2) * 512 + c.wl * 32 + c.quad * 8);
  const unsigned base_hw = (unsigned)(c.b * HP + c.h0) * WP + c.w0;
  const int lg = lane >> 2;            // 0..15 slot-in-group
  c.mask = 0;
#pragma unroll
  for (int t = 0; t < 6; ++t) {
    const int s = (c.wv * 12 + t) * 16 + lg;   // <= 287, no clamp needed
    const int x = s / 18, y = s - x * 18;
    const int wh = SW ? y : x, ww = SW ? x : y;
    c.goff[t] = (base_hw + (unsigned)(wh * WP + ww)) * 256u + (lane & 3) * 8u;
    if (y >= 12) c.mask |= (1u << t);
    if (s > 227) c.mask |= (1u << (6 + t));    // s+96 > 323 -> dummy slot
  }
  c.lds_stage = (unsigned)(c.wv * 12) * 1024u + (unsigned)lane * 16u;
  return c;
}

template<int SW>
__device__ __forceinline__ void stage_cbB(const _Float16* __restrict__ src,
                                          char* sbuf, const CtxB& c, int buf, int cb)
{
  constexpr int D0 = SW ? (6 * WP + 5) * 256 : (5 * WP + 6) * 256;
  constexpr int D1 = SW ? (6 - 12 * WP) * 256 : (6 * WP - 12) * 256;
  char* l0 = sbuf + buf * BUF_Q + c.lds_stage;
#pragma unroll
  for (int t = 0; t < 6; ++t) {
    const _Float16* g = src + c.goff[t] + cb * 32;
    __builtin_amdgcn_global_load_lds(
        (const __attribute__((address_space(1))) void*)g,
        (__attribute__((address_space(3))) void*)(l0 + t * 1024), 16, 0, 0);
  }
#pragma unroll
  for (int t = 0; t < 6; ++t) {
    const int d = ((c.mask >> (6 + t)) & 1) ? 0
                : (((c.mask >> t) & 1) ? D1 : D0);
    const _Float16* g = src + (int)(c.goff[t] + (unsigned)d) + cb * 32;
    __builtin_amdgcn_global_load_lds(
        (const __attribute__((address_space(1))) void*)g,
        (__attribute__((address_space(3))) void*)(l0 + (6 + t) * 1024), 16, 0, 0);
  }
}

template<int S>
__device__ __forceinline__ void conv_accumB(const _Float16* __restrict__ src,
                                            const _Float16* __restrict__ wkb,
                                            char* sbuf, const CtxB& c, f32x4 acc[2][16])
{
  const _Float16* A0 = wkb + c.aoff;
  stage_cbB<S>(src, sbuf, c, 0, 0);
#pragma unroll 1
  for (int cb = 0; cb < 8; ++cb) {
    __syncthreads();
    if (cb < 7) stage_cbB<S>(src, sbuf, c, (cb + 1) & 1, cb + 1);
    conv_cb_compute<S>((const _Float16*)(sbuf + (cb & 1) * BUF_Q),
                       A0 + cb * (9 * 8192), c.wl, c.quad, acc);
  }
  __syncthreads();
}

// ---------------- merged main conv: p12 (1152 items) + c1conv (576) -------
__global__ __launch_bounds__(256, 2) void k_conv_main(
    const _Float16* __restrict__ xpad, const _Float16* __restrict__ wk,
    const float* __restrict__ bias1, const float* __restrict__ bias2,
    const float* __restrict__ bias_p, const float* __restrict__ bias_c1,
    float* __restrict__ u_pad, float* __restrict__ v_pad,
    _Float16* __restrict__ tmp)
{
  __shared__ __align__(16) char smem[SMEM_Q];
  const int lin = xcd_swz(blockIdx.x, 1728);
  f32x4 acc[2][16];
  ZERO_ACCQ(acc)
  if (lin < 1152) {
    const int set = lin >= 576;
    const int rem = lin - set * 576;
    const int spatial = rem >> 1, ch = rem & 1;
    if (set == 0) {
      CtxQ c = make_ctxQ<0>(spatial, ch);
      conv_accumQ<0>(xpad, wk, smem, c, acc);
#pragma unroll
      for (int i = 0; i < 2; ++i) {
        const int co = (ch * 8 + c.wv * 2 + i) * 16 + c.quad * 4;
        const float4 bs = *(const float4*)(bias1 + co);
        float m0 = 0.f, m1 = 0.f, m2 = 0.f, m3 = 0.f;
#pragma unroll
        for (int j = 0; j < 16; ++j) {             // j = h: in-lane max over h
          m0 = fmaxf(m0, acc[i][j][0] + bs.x);
          m1 = fmaxf(m1, acc[i][j][1] + bs.y);
          m2 = fmaxf(m2, acc[i][j][2] + bs.z);
          m3 = fmaxf(m3, acc[i][j][3] + bs.w);
        }
        unsigned* tgt = (unsigned*)(u_pad + ((size_t)c.b * 98 + (c.w0 + c.wl + 1)) * 256 + co);
        atomicMax(tgt + 0, __float_as_uint(m0));
        atomicMax(tgt + 1, __float_as_uint(m1));
        atomicMax(tgt + 2, __float_as_uint(m2));
        atomicMax(tgt + 3, __float_as_uint(m3));
      }
    } else {
      CtxQ c = make_ctxQ<1>(spatial, ch);
      conv_accumQ<1>(xpad, wk + WSET, smem, c, acc);
#pragma unroll
      for (int i = 0; i < 2; ++i) {
        const int co = (ch * 8 + c.wv * 2 + i) * 16 + c.quad * 4;
        const float4 bs = *(const float4*)(bias2 + co);
        float m0 = 0.f, m1 = 0.f, m2 = 0.f, m3 = 0.f;
#pragma unroll
        for (int j = 0; j < 16; ++j) {             // j = w: in-lane max over w
          m0 = fmaxf(m0, acc[i][j][0] + bs.x);
          m1 = fmaxf(m1, acc[i][j][1] + bs.y);
          m2 = fmaxf(m2, acc[i][j][2] + bs.z);
          m3 = fmaxf(m3, acc[i][j][3] + bs.w);
        }
        unsigned* tgt = (unsigned*)(v_pad + ((size_t)c.b * 98 + (c.h0 + c.wl + 1)) * 256 + co);
        atomicMax(tgt + 0, __float_as_uint(m0));
        atomicMax(tgt + 1, __float_as_uint(m1));
        atomicMax(tgt + 2, __float_as_uint(m2));
        atomicMax(tgt + 3, __float_as_uint(m3));
      }
    }
  } else {
    const int idx = lin - 1152;
    const int spatial = idx >> 1, ch = idx & 1;
    CtxQ c = make_ctxQ<0>(spatial, ch);
    conv_accumQ<0>(xpad, wk + (size_t)3 * WSET, smem, c, acc);
    const int w = c.w0 + c.wl;
#pragma unroll
    for (int i = 0; i < 2; ++i) {
      const int co = (ch * 8 + c.wv * 2 + i) * 16 + c.quad * 4;
      float4 bs = *(const float4*)(bias_p + co);
      const float4 b2 = *(const float4*)(bias_c1 + co);
      bs.x += b2.x; bs.y += b2.y; bs.z += b2.z; bs.w += b2.w;
#pragma unroll
      for (int j = 0; j < 16; ++j) {
        const int h = c.h0 + j;
        f16x4v pk;
        pk[0] = (_Float16)(acc[i][j][0] + bs.x);
        pk[1] = (_Float16)(acc[i][j][1] + bs.y);
        pk[2] = (_Float16)(acc[i][j][2] + bs.z);
        pk[3] = (_Float16)(acc[i][j][3] + bs.w);
        *(f16x4v*)(tmp + ((size_t)(c.b * 96 + h) * 96 + w) * 256 + co) = pk;
      }
    }
  }
}

// ---------------- 1D convs of u,v with case-summed weights ----------------
__global__ __launch_bounds__(256, 2) void k_uv1d(
    const float* __restrict__ u_pad, const float* __restrict__ v_pad,
    const _Float16* __restrict__ wuv, float* __restrict__ u2, float* __restrict__ v2)
{
  const int id = blockIdx.x;
  const int py = blockIdx.y;                     // 0..1 pos half
  const int b = id & 7, cs = (id >> 3) % 3, t = id / 24;
  const float* src = t ? v_pad : u_pad;
  float* dst = t ? v2 : u2;
  const _Float16* A0 = wuv + (size_t)(t * 3 + cs) * WUV_SET;
  const int lane = threadIdx.x & 63, wv = threadIdx.x >> 6;
  const int quad = lane >> 4, l16 = lane & 15;

  f32x4 acc[4][3];
#pragma unroll
  for (int i = 0; i < 4; ++i)
#pragma unroll
    for (int j = 0; j < 3; ++j) acc[i][j] = (f32x4){0.f, 0.f, 0.f, 0.f};

#pragma unroll 1
  for (int kb = 0; kb < 24; ++kb) {
    const int dw = kb >> 3, cb = kb & 7;
    f16x8 bf[3];
#pragma unroll
    for (int j = 0; j < 3; ++j) {
      const int pos = py * 48 + j * 16 + l16;
      const float* p = src + ((size_t)b * 98 + (pos + dw)) * 256 + cb * 32 + quad * 8;
      const float4 x0 = *(const float4*)p;
      const float4 x1 = *(const float4*)(p + 4);
      f16x8 v;
      v[0] = (_Float16)x0.x; v[1] = (_Float16)x0.y; v[2] = (_Float16)x0.z; v[3] = (_Float16)x0.w;
      v[4] = (_Float16)x1.x; v[5] = (_Float16)x1.y; v[6] = (_Float16)x1.z; v[7] = (_Float16)x1.w;
      bf[j] = v;
    }
    f16x8 af[4];
#pragma unroll
    for (int i = 0; i < 4; ++i)
      af[i] = *(const f16x8*)(A0 + (size_t)(kb * 16 + wv * 4 + i) * 512 + l16 * 32 + quad * 8);
#pragma unroll
    for (int i = 0; i < 4; ++i)
#pragma unroll
      for (int j = 0; j < 3; ++j)
        acc[i][j] = __builtin_amdgcn_mfma_f32_16x16x32_f16(af[i], bf[j], acc[i][j], 0, 0, 0);
  }
#pragma unroll
  for (int i = 0; i < 4; ++i)
#pragma unroll
    for (int j = 0; j < 3; ++j) {
      const int pos = py * 48 + j * 16 + l16;
      const int co = wv * 64 + i * 16 + quad * 4;
      *(f32x4*)(dst + ((size_t)(cs * 8 + b) * 96 + pos) * 256 + co) = acc[i][j];
    }
}

// ---------------- c1 epilogue: tmp + U' + V', relu -> r_pad NHWC f16 ------
__global__ __launch_bounds__(256, 8) void k_epi_c1(
    const _Float16* __restrict__ tmp,
    const float* __restrict__ u2, const float* __restrict__ v2,
    _Float16* __restrict__ rpad)
{
  const int gid = blockIdx.x;                    // 0..767
  const int b = gid / 96, h = gid - b * 96;
  const int hcase = (h == 0) ? 0 : ((h == 95) ? 2 : 1);
  const size_t tbase = (size_t)(b * 96 + h) * 96 * 256;
#pragma unroll 1
  for (int it = 0; it < 12; ++it) {
    const int chunk = it * 256 + threadIdx.x;    // 0..3071
    const int w = chunk >> 5;
    const int co8 = (chunk & 31) * 8;
    const int wcase = (w == 0) ? 0 : ((w == 95) ? 2 : 1);
    const f16x8 t = *(const f16x8*)(tmp + tbase + (size_t)w * 256 + co8);
    const float* up = u2 + ((size_t)(hcase * 8 + b) * 96 + w) * 256 + co8;
    const float* vp = v2 + ((size_t)(wcase * 8 + b) * 96 + h) * 256 + co8;
    const float4 u0 = *(const float4*)up, u1 = *(const float4*)(up + 4);
    const float4 v0 = *(const float4*)vp, v1 = *(const float4*)(vp + 4);
    f16x8 r;
    r[0] = (_Float16)fmaxf((float)t[0] + u0.x + v0.x, 0.f);
    r[1] = (_Float16)fmaxf((float)t[1] + u0.y + v0.y, 0.f);
    r[2] = (_Float16)fmaxf((float)t[2] + u0.z + v0.z, 0.f);
    r[3] = (_Float16)fmaxf((float)t[3] + u0.w + v0.w, 0.f);
    r[4] = (_Float16)fmaxf((float)t[4] + u1.x + v1.x, 0.f);
    r[5] = (_Float16)fmaxf((float)t[5] + u1.y + v1.y, 0.f);
    r[6] = (_Float16)fmaxf((float)t[6] + u1.z + v1.z, 0.f);
    r[7] = (_Float16)fmaxf((float)t[7] + u1.w + v1.w, 0.f);
    *(f16x8*)(rpad + ((size_t)(b * HP + h + 1) * WP + w + 1) * 256 + co8) = r;
  }
}

// ---------------- final conv, relu, NCHW f32 to d_out ---------------------
__global__ __launch_bounds__(128, 2) void k_conv_c2(
    const _Float16* __restrict__ rpad, const _Float16* __restrict__ wkc2,
    const float* __restrict__ bias, float* __restrict__ dout)
{
  __shared__ __align__(16) char smem[SMEM_Q];
  const int lin = xcd_swz(blockIdx.x, 1152);
  const int spatial = lin >> 2, ch = lin & 3;
  CtxB c = make_ctxB<0>(spatial, ch);
  f32x4 acc[2][16];
  ZERO_ACCQ(acc)
  conv_accumB<0>(rpad, wkc2, smem, c, acc);

  const int w = c.w0 + c.wl;
#pragma unroll
  for (int j = 0; j < 16; ++j) {
    const int h = c.h0 + j;
    float* op = dout + (size_t)c.b * 2359296 + h * 96 + w;
#pragma unroll
    for (int i = 0; i < 2; ++i) {
      const int co = (ch * 4 + c.wv * 2 + i) * 16 + c.quad * 4;
      const float4 bs = *(const float4*)(bias + co);
      op[(size_t)(co + 0) * 9216] = fmaxf(acc[i][j][0] + bs.x, 0.f);
      op[(size_t)(co + 1) * 9216] = fmaxf(acc[i][j][1] + bs.y, 0.f);
      op[(size_t)(co + 2) * 9216] = fmaxf(acc[i][j][2] + bs.z, 0.f);
      op[(size_t)(co + 3) * 9216] = fmaxf(acc[i][j][3] + bs.w, 0.f);
    }
  }
}

// ---------------- aux kernels ---------------------------------------------
// Zero the 1-px halo ring of x_pad (z=0) and r_pad (z=1). 388 border pos/img.
__global__ void k_border(_Float16* __restrict__ xpad, _Float16* __restrict__ rpad)
{
  const int idx = blockIdx.x, b = blockIdx.y;
  _Float16* buf = blockIdx.z ? rpad : xpad;
  int h, w;
  if (idx < 98)       { h = 0;  w = idx; }
  else if (idx < 196) { h = 97; w = idx - 98; }
  else { const int r = idx - 196; h = 1 + (r >> 1); w = (r & 1) ? 97 : 0; }
  buf[((size_t)(b * HP + h) * WP + w) * 256 + threadIdx.x] = (_Float16)0.f;
}

__global__ void k_pack_x(const float* __restrict__ x, _Float16* __restrict__ xpad)
{
  __shared__ float tile[32][33];
  const int bh = blockIdx.x;
  const int b = bh / 96, h = bh - b * 96;
  const int c0 = blockIdx.y * 32, w0 = blockIdx.z * 32;
  const int tx = threadIdx.x & 31, ty = threadIdx.x >> 5;
#pragma unroll
  for (int i = 0; i < 4; ++i) {
    int cI = c0 + ty + i * 8;
    tile[ty + i * 8][tx] = x[(((size_t)b * 256 + cI) * 96 + h) * 96 + w0 + tx];
  }
  __syncthreads();
#pragma unroll
  for (int i = 0; i < 4; ++i) {
    int w = w0 + ty + i * 8;
    xpad[((size_t)(b * HP + h + 1) * WP + (w + 1)) * 256 + c0 + tx] =
        (_Float16)tile[tx][ty + i * 8];
  }
}

// main conv weights -> tiled layout: idx = ((cb*9+tap)*16 + cog)*512 + m*32 + kk
__global__ void k_repack_w(const float* w0, const float* g0, const float* w1, const float* g1,
                           const float* w2, const float* g2, const float* w3, const float* g3,
                           const float* w4, const float* g4, _Float16* __restrict__ wk)
{
  const int set = blockIdx.y;
  const float* w; const float* g;
  switch (set) {
    case 0: w = w0; g = g0; break;
    case 1: w = w1; g = g1; break;
    case 2: w = w2; g = g2; break;
    case 3: w = w3; g = g3; break;
    default: w = w4; g = g4; break;
  }
  const int t = blockIdx.x * 256 + threadIdx.x;   // co*256 + ci
  const int co = t >> 8, ci = t & 255;
  const int cb = ci >> 5, kk = ci & 31, cog = co >> 4, m = co & 15;
  const float gv = g[co];
  const float* src = w + ((size_t)co * 256 + ci) * 9;
  _Float16* dst = wk + (size_t)set * WSET + cog * 512 + m * 32 + kk;
#pragma unroll
  for (int tap = 0; tap < 9; ++tap)
    dst[(cb * 9 + tap) * 8192] = (_Float16)(src[tap] * gv);
}

// case-summed 1D weights for U'/V'
__global__ void k_repack_uvw(const float* __restrict__ wp, const float* __restrict__ gp,
                             _Float16* __restrict__ wuv)
{
  const int tcs = blockIdx.y;                             // 0..5 = t*3+cs
  const int tt = tcs / 3, cs = tcs - tt * 3;
  const int idx = blockIdx.x * 256 + threadIdx.x;         // co*256 + ci
  const int co = idx >> 8, ci = idx & 255;
  const float gv = gp[co];
  const float* src = wp + ((size_t)co * 256 + ci) * 9;    // [dh][dw]
  const int lo = (cs == 0) ? 1 : 0, hi = (cs == 2) ? 1 : 2;
  _Float16* base = wuv + (size_t)tcs * WUV_SET;
#pragma unroll
  for (int d = 0; d < 3; ++d) {
    float s = 0.f;
    for (int e = lo; e <= hi; ++e)
      s += (tt == 0) ? src[e * 3 + d] : src[d * 3 + e];
    const int k = d * 256 + ci;
    const int kb = k >> 5, kk = k & 31;
    base[(size_t)(kb * 16 + (co >> 4)) * 512 + (co & 15) * 32 + kk] = (_Float16)(s * gv);
  }
}

// ---------------- launcher -------------------------------------------------
extern "C" void kernel_launch(void* const* d_in, const int* in_sizes, int n_in,
                              void* d_out, int out_size, void* d_ws, size_t ws_size,
                              hipStream_t stream)
{
  const float* x    = (const float*)d_in[0];
  const float* w_p1 = (const float*)d_in[1];
  const float* g_p1 = (const float*)d_in[2];
  const float* b_p1 = (const float*)d_in[3];
  const float* w_p2 = (const float*)d_in[4];
  const float* g_p2 = (const float*)d_in[5];
  const float* b_p2 = (const float*)d_in[6];
  const float* w_p  = (const float*)d_in[7];
  const float* g_p  = (const float*)d_in[8];
  const float* b_p  = (const float*)d_in[9];
  const float* w_c1 = (const float*)d_in[10];
  const float* g_c1 = (const float*)d_in[11];
  const float* b_c1 = (const float*)d_in[12];
  const float* w_c2 = (const float*)d_in[13];
  const float* g_c2 = (const float*)d_in[14];
  const float* b_c2 = (const float*)d_in[15];

  char* ws = (char*)d_ws;
  size_t off = 0;
  _Float16* x_pad = (_Float16*)(ws + off); off += XPAD_E * 2;
  _Float16* r_pad = (_Float16*)(ws + off); off += XPAD_E * 2;
  _Float16* wks   = (_Float16*)(ws + off); off += (size_t)5 * WSET * 2;
  _Float16* wuv   = (_Float16*)(ws + off); off += (size_t)6 * WUV_SET * 2;
  float*    u_pad = (float*)(ws + off);    off += UVP_E * 4;
  float*    v_pad = (float*)(ws + off);    off += UVP_E * 4;
  float*    u2    = (float*)(ws + off);    off += UV2_E * 4;
  float*    v2    = (float*)(ws + off);    off += UV2_E * 4;
  _Float16* tmp   = (_Float16*)d_out;      // c1 conv scratch; free until c2
  (void)ws_size; (void)in_sizes; (void)n_in; (void)out_size;

  hipMemsetAsync(u_pad, 0, UVP_E * 4, stream);     // atomicMax targets + zero pad
  hipMemsetAsync(v_pad, 0, UVP_E * 4, stream);

  k_border    <<<dim3(388, 8, 2), 256, 0, stream>>>(x_pad, r_pad);
  k_pack_x    <<<dim3(768, 8, 3), 256, 0, stream>>>(x, x_pad);
  k_repack_w  <<<dim3(256, 5),    256, 0, stream>>>(w_p1, g_p1, w_p2, g_p2, w_p, g_p,
                                                    w_c1, g_c1, w_c2, g_c2, wks);
  k_repack_uvw<<<dim3(256, 6),    256, 0, stream>>>(w_p, g_p, wuv);
  k_conv_main <<<1728, 256, 0, stream>>>(x_pad, wks, b_p1, b_p2, b_p, b_c1,
                                         u_pad, v_pad, tmp);
  k_uv1d      <<<dim3(48, 2), 256, 0, stream>>>(u_pad, v_pad, wuv, u2, v2);
  k_epi_c1    <<<768, 256, 0, stream>>>(tmp, u2, v2, r_pad);
  k_conv_c2   <<<1152, 128, 0, stream>>>(r_pad, wks + (size_t)4 * WSET, b_c2,
                                         (float*)d_out);
}

// Round 9
// 527.176 us; speedup vs baseline: 1.3811x; 1.3811x over previous
//
#include <hip/hip_runtime.h>

// ct_layer round 16: DPP o-shift, register-disciplined retry (main only).
//   R15 failed via scratch spill (WRITE_SIZE 551MB): fully-unrolled o-loop let
//   the scheduler pipeline DPP(o+1) vs MFMA(o), holding two cache generations
//   live -> spill. Correctness of the DPP shift + wl==15 patch was PROVEN
//   (absmax identical). R16 containment:
//     - #pragma unroll 1 on the o loop (hard live-range boundary);
//     - DPP core only in k_conv_main; c2 keeps R14's plain 60-read body.
//   Everything else identical to R14 (522us best).

typedef _Float16 f16x8 __attribute__((ext_vector_type(8)));
typedef _Float16 f16x4v __attribute__((ext_vector_type(4)));
typedef float f32x4 __attribute__((ext_vector_type(4)));

#define HP 98
#define WP 98
#define KTOT 2304
#define WSET (256*KTOT)                // 589824 elems per weight set
#define XPAD_E ((size_t)8*HP*WP*256)
#define UVP_E  ((size_t)8*98*256)      // u_pad/v_pad f32 (atomic targets)
#define UV2_E  ((size_t)3*8*96*256)    // u2/v2 f32 [case][b][pos][co]
#define WUV_SET 196608                 // 256co * 768k per (t,case)

// XCD-aware block swizzle (requires nwg % 8 == 0).
__device__ __forceinline__ int xcd_swz(int bid, int nwg)
{
  return (bid & 7) * (nwg >> 3) + (bid >> 3);
}

#define BUF_Q 24576
#define SMEM_Q 49152

// lane shift within 16-lane rows: dst[wl] = src[wl+1] (proven in R15)
__device__ __forceinline__ f16x8 dpp_shl1(f16x8 v)
{
  union U { f16x8 h; int d[4]; } a, r;
  a.h = v;
#pragma unroll
  for (int k = 0; k < 4; ++k)
    r.d[k] = __builtin_amdgcn_update_dpp(0, a.d[k], 0x101, 0xf, 0xf, true);
  return r.h;
}

// ---- DPP per-cb body (main): 18-row read once + in-register o-shift ------
// S: tap = (S==0) ? p*3+o : o*3+p  (weight layout tap = dh*3+dw).
template<int S>
__device__ __forceinline__ void conv_cb_dpp(const _Float16* __restrict__ B,
                                            const _Float16* __restrict__ A,
                                            int wl, int quad, f32x4 acc[2][16])
{
  f16x8 cache[18];
#pragma unroll
  for (int r = 0; r < 18; ++r)
    cache[r] = *(const f16x8*)(B + (r * 18 + wl) * 32 + quad * 8);
#pragma unroll 1
  for (int o = 0; o < 3; ++o) {
    if (o) {
#pragma unroll
      for (int r = 0; r < 18; ++r) cache[r] = dpp_shl1(cache[r]);
      if (wl == 15) {
#pragma unroll
        for (int r = 0; r < 18; ++r)
          cache[r] = *(const f16x8*)(B + (r * 18 + 15 + o) * 32 + quad * 8);
      }
    }
#pragma unroll
    for (int p = 0; p < 3; ++p) {
      const int tap = (S == 0) ? p * 3 + o : o * 3 + p;
      const f16x8 af0 = *(const f16x8*)(A + tap * 8192);
      const f16x8 af1 = *(const f16x8*)(A + tap * 8192 + 512);
#pragma unroll
      for (int j = 0; j < 16; ++j) {
        acc[0][j] = __builtin_amdgcn_mfma_f32_16x16x32_f16(af0, cache[j + p], acc[0][j], 0, 0, 0);
        acc[1][j] = __builtin_amdgcn_mfma_f32_16x16x32_f16(af1, cache[j + p], acc[1][j], 0, 0, 0);
      }
    }
  }
}

// ---- plain per-cb body (c2): R14's proven 60-read version ----------------
template<int S>
__device__ __forceinline__ void conv_cb_plain(const _Float16* __restrict__ B,
                                              const _Float16* __restrict__ A,
                                              int wl, int quad, f32x4 acc[2][16])
{
#pragma unroll
  for (int o = 0; o < 3; ++o) {
    f16x8 af[3][2];
#pragma unroll
    for (int p = 0; p < 3; ++p) {
      const int tap = (S == 0) ? p * 3 + o : o * 3 + p;
#pragma unroll
      for (int i = 0; i < 2; ++i)
        af[p][i] = *(const f16x8*)(A + tap * 8192 + i * 512);
    }
#pragma unroll
    for (int jh = 0; jh < 2; ++jh) {
      f16x8 cache[10];
#pragma unroll
      for (int r = 0; r < 10; ++r)
        cache[r] = *(const f16x8*)(B + ((jh * 8 + r) * 18 + wl + o) * 32 + quad * 8);
#pragma unroll
      for (int p = 0; p < 3; ++p)
#pragma unroll
        for (int i = 0; i < 2; ++i)
#pragma unroll
          for (int j = 0; j < 8; ++j)
            acc[i][jh * 8 + j] = __builtin_amdgcn_mfma_f32_16x16x32_f16(
                af[p][i], cache[j + p], acc[i][jh * 8 + j], 0, 0, 0);
    }
  }
}

// ---------------- Q16 conv core (4-wave): 32co x 256n per wave ------------
struct CtxQ {
  unsigned goff[6];
  unsigned lds_stage;
  unsigned aoff;
  int wl, quad, wv;
  int b, h0, w0;
};

template<int SW>
__device__ __forceinline__ CtxQ make_ctxQ(int spatial, int ch)
{
  CtxQ c;
  c.b = spatial / 36;
  const int tt = spatial - c.b * 36;
  const int ht = tt / 6, wt = tt - ht * 6;
  c.h0 = ht * 16; c.w0 = wt * 16;
  const int tid = threadIdx.x, lane = tid & 63;
  c.wv = tid >> 6;
  c.quad = lane >> 4; c.wl = lane & 15;
  c.aoff = (unsigned)((ch * 8 + c.wv * 2) * 512 + c.wl * 32 + c.quad * 8);
  const unsigned base_hw = (unsigned)(c.b * HP + c.h0) * WP + c.w0;
#pragma unroll
  for (int t = 0; t < 6; ++t) {
    int s = (c.wv * 6 + t) * 16 + (lane >> 2);   // 0..383; 324..383 dummy
    if (s > 323) s = 323;
    const int x = s / 18, y = s - x * 18;
    const int wh = SW ? y : x, ww = SW ? x : y;
    c.goff[t] = (base_hw + (unsigned)(wh * WP + ww)) * 256u + (lane & 3) * 8u;
  }
  c.lds_stage = (unsigned)(c.wv * 6) * 1024u + (unsigned)lane * 16u;
  return c;
}

__device__ __forceinline__ void stage_cbQ(const _Float16* __restrict__ src,
                                          char* sbuf, const CtxQ& c, int buf, int cb)
{
  char* l0 = sbuf + buf * BUF_Q + c.lds_stage;
#pragma unroll
  for (int t = 0; t < 6; ++t) {
    const _Float16* g = src + c.goff[t] + cb * 32;
    __builtin_amdgcn_global_load_lds(
        (const __attribute__((address_space(1))) void*)g,
        (__attribute__((address_space(3))) void*)(l0 + t * 1024), 16, 0, 0);
  }
}

template<int S>
__device__ __forceinline__ void conv_accumQ(const _Float16* __restrict__ src,
                                            const _Float16* __restrict__ wkb,
                                            char* sbuf, const CtxQ& c, f32x4 acc[2][16])
{
  const _Float16* A0 = wkb + c.aoff;
  stage_cbQ(src, sbuf, c, 0, 0);
#pragma unroll 1
  for (int cb = 0; cb < 8; ++cb) {
    __syncthreads();
    if (cb < 7) stage_cbQ(src, sbuf, c, (cb + 1) & 1, cb + 1);
    conv_cb_dpp<S>((const _Float16*)(sbuf + (cb & 1) * BUF_Q),
                   A0 + cb * (9 * 8192), c.wl, c.quad, acc);
  }
  __syncthreads();
}

#define ZERO_ACCQ(acc) \
  _Pragma("unroll") for (int i = 0; i < 2; ++i) \
  _Pragma("unroll") for (int j = 0; j < 16; ++j) acc[i][j] = (f32x4){0.f,0.f,0.f,0.f};

// ---------------- Q16b conv core (2-wave, for c2): 64co x 256n per block --
struct CtxB {
  unsigned goff[6];
  unsigned mask;                       // bits 0-5: y>=12 (delta sel); 6-11: dummy
  unsigned lds_stage;
  unsigned aoff;
  int wl, quad, wv;
  int b, h0, w0;
};

template<int SW>
__device__ __forceinline__ CtxB make_ctxB(int spatial, int ch)
{
  CtxB c;
  c.b = spatial / 36;
  const int tt = spatial - c.b * 36;
  const int ht = tt / 6, wt = tt - ht * 6;
  c.h0 = ht * 16; c.w0 = wt * 16;
  const int tid = threadIdx.x, lane = tid & 63;
  c.wv = tid >> 6;                     // 0..1
  c.quad = lane >> 4; c.wl = lane & 15;
  c.aoff = (unsigned)((ch * 4 + c.wv * 2) * 512 + c.wl * 32 + c.quad * 8);
  const unsigned base_hw = (unsigned)(c.b * HP + c.h0) * WP + c.w0;
  const int lg = lane >> 2;            // 0..15 slot-in-group
  c.mask = 0;
#pragma unroll
  for (int t = 0; t < 6; ++t) {
    const int s = (c.wv * 12 + t) * 16 + lg;   // <= 287, no clamp needed
    const int x = s / 18, y = s - x * 18;
    const int wh = SW ? y : x, ww = SW ? x : y;
    c.goff[t] = (base_hw + (unsigned)(wh * WP + ww)) * 256u + (lane & 3) * 8u;
    if (y >= 12) c.mask |= (1u << t);
    if (s > 227) c.mask |= (1u << (6 + t));    // s+96 > 323 -> dummy slot
  }
  c.lds_stage = (unsigned)(c.wv * 12) * 1024u + (unsigned)lane * 16u;
  return c;
}

template<int SW>
__device__ __forceinline__ void stage_cbB(const _Float16* __restrict__ src,
                                          char* sbuf, const CtxB& c, int buf, int cb)
{
  constexpr int D0 = SW ? (6 * WP + 5) * 256 : (5 * WP + 6) * 256;
  constexpr int D1 = SW ? (6 - 12 * WP) * 256 : (6 * WP - 12) * 256;
  char* l0 = sbuf + buf * BUF_Q + c.lds_stage;
#pragma unroll
  for (int t = 0; t < 6; ++t) {
    const _Float16* g = src + c.goff[t] + cb * 32;
    __builtin_amdgcn_global_load_lds(
        (const __attribute__((address_space(1))) void*)g,
        (__attribute__((address_space(3))) void*)(l0 + t * 1024), 16, 0, 0);
  }
#pragma unroll
  for (int t = 0; t < 6; ++t) {
    const int d = ((c.mask >> (6 + t)) & 1) ? 0
                : (((c.mask >> t) & 1) ? D1 : D0);
    const _Float16* g = src + (int)(c.goff[t] + (unsigned)d) + cb * 32;
    __builtin_amdgcn_global_load_lds(
        (const __attribute__((address_space(1))) void*)g,
        (__attribute__((address_space(3))) void*)(l0 + (6 + t) * 1024), 16, 0, 0);
  }
}

template<int S>
__device__ __forceinline__ void conv_accumB(const _Float16* __restrict__ src,
                                            const _Float16* __restrict__ wkb,
                                            char* sbuf, const CtxB& c, f32x4 acc[2][16])
{
  const _Float16* A0 = wkb + c.aoff;
  stage_cbB<S>(src, sbuf, c, 0, 0);
#pragma unroll 1
  for (int cb = 0; cb < 8; ++cb) {
    __syncthreads();
    if (cb < 7) stage_cbB<S>(src, sbuf, c, (cb + 1) & 1, cb + 1);
    conv_cb_plain<S>((const _Float16*)(sbuf + (cb & 1) * BUF_Q),
                     A0 + cb * (9 * 8192), c.wl, c.quad, acc);
  }
  __syncthreads();
}

// ---------------- merged main conv: p12 (1152 items) + c1conv (576) -------
__global__ __launch_bounds__(256, 2) void k_conv_main(
    const _Float16* __restrict__ xpad, const _Float16* __restrict__ wk,
    const float* __restrict__ bias1, const float* __restrict__ bias2,
    const float* __restrict__ bias_p, const float* __restrict__ bias_c1,
    float* __restrict__ u_pad, float* __restrict__ v_pad,
    _Float16* __restrict__ tmp)
{
  __shared__ __align__(16) char smem[SMEM_Q];
  const int lin = xcd_swz(blockIdx.x, 1728);
  f32x4 acc[2][16];
  ZERO_ACCQ(acc)
  if (lin < 1152) {
    const int set = lin >= 576;
    const int rem = lin - set * 576;
    const int spatial = rem >> 1, ch = rem & 1;
    if (set == 0) {
      CtxQ c = make_ctxQ<0>(spatial, ch);
      conv_accumQ<0>(xpad, wk, smem, c, acc);
#pragma unroll
      for (int i = 0; i < 2; ++i) {
        const int co = (ch * 8 + c.wv * 2 + i) * 16 + c.quad * 4;
        const float4 bs = *(const float4*)(bias1 + co);
        float m0 = 0.f, m1 = 0.f, m2 = 0.f, m3 = 0.f;
#pragma unroll
        for (int j = 0; j < 16; ++j) {             // j = h: in-lane max over h
          m0 = fmaxf(m0, acc[i][j][0] + bs.x);
          m1 = fmaxf(m1, acc[i][j][1] + bs.y);
          m2 = fmaxf(m2, acc[i][j][2] + bs.z);
          m3 = fmaxf(m3, acc[i][j][3] + bs.w);
        }
        unsigned* tgt = (unsigned*)(u_pad + ((size_t)c.b * 98 + (c.w0 + c.wl + 1)) * 256 + co);
        atomicMax(tgt + 0, __float_as_uint(m0));
        atomicMax(tgt + 1, __float_as_uint(m1));
        atomicMax(tgt + 2, __float_as_uint(m2));
        atomicMax(tgt + 3, __float_as_uint(m3));
      }
    } else {
      CtxQ c = make_ctxQ<1>(spatial, ch);
      conv_accumQ<1>(xpad, wk + WSET, smem, c, acc);
#pragma unroll
      for (int i = 0; i < 2; ++i) {
        const int co = (ch * 8 + c.wv * 2 + i) * 16 + c.quad * 4;
        const float4 bs = *(const float4*)(bias2 + co);
        float m0 = 0.f, m1 = 0.f, m2 = 0.f, m3 = 0.f;
#pragma unroll
        for (int j = 0; j < 16; ++j) {             // j = w: in-lane max over w
          m0 = fmaxf(m0, acc[i][j][0] + bs.x);
          m1 = fmaxf(m1, acc[i][j][1] + bs.y);
          m2 = fmaxf(m2, acc[i][j][2] + bs.z);
          m3 = fmaxf(m3, acc[i][j][3] + bs.w);
        }
        unsigned* tgt = (unsigned*)(v_pad + ((size_t)c.b * 98 + (c.h0 + c.wl + 1)) * 256 + co);
        atomicMax(tgt + 0, __float_as_uint(m0));
        atomicMax(tgt + 1, __float_as_uint(m1));
        atomicMax(tgt + 2, __float_as_uint(m2));
        atomicMax(tgt + 3, __float_as_uint(m3));
      }
    }
  } else {
    const int idx = lin - 1152;
    const int spatial = idx >> 1, ch = idx & 1;
    CtxQ c = make_ctxQ<0>(spatial, ch);
    conv_accumQ<0>(xpad, wk + (size_t)3 * WSET, smem, c, acc);
    const int w = c.w0 + c.wl;
#pragma unroll
    for (int i = 0; i < 2; ++i) {
      const int co = (ch * 8 + c.wv * 2 + i) * 16 + c.quad * 4;
      float4 bs = *(const float4*)(bias_p + co);
      const float4 b2 = *(const float4*)(bias_c1 + co);
      bs.x += b2.x; bs.y += b2.y; bs.z += b2.z; bs.w += b2.w;
#pragma unroll
      for (int j = 0; j < 16; ++j) {
        const int h = c.h0 + j;
        f16x4v pk;
        pk[0] = (_Float16)(acc[i][j][0] + bs.x);
        pk[1] = (_Float16)(acc[i][j][1] + bs.y);
        pk[2] = (_Float16)(acc[i][j][2] + bs.z);
        pk[3] = (_Float16)(acc[i][j][3] + bs.w);
        *(f16x4v*)(tmp + ((size_t)(c.b * 96 + h) * 96 + w) * 256 + co) = pk;
      }
    }
  }
}

// ---------------- 1D convs of u,v with case-summed weights ----------------
__global__ __launch_bounds__(256, 2) void k_uv1d(
    const float* __restrict__ u_pad, const float* __restrict__ v_pad,
    const _Float16* __restrict__ wuv, float* __restrict__ u2, float* __restrict__ v2)
{
  const int id = blockIdx.x;
  const int py = blockIdx.y;                     // 0..1 pos half
  const int b = id & 7, cs = (id >> 3) % 3, t = id / 24;
  const float* src = t ? v_pad : u_pad;
  float* dst = t ? v2 : u2;
  const _Float16* A0 = wuv + (size_t)(t * 3 + cs) * WUV_SET;
  const int lane = threadIdx.x & 63, wv = threadIdx.x >> 6;
  const int quad = lane >> 4, l16 = lane & 15;

  f32x4 acc[4][3];
#pragma unroll
  for (int i = 0; i < 4; ++i)
#pragma unroll
    for (int j = 0; j < 3; ++j) acc[i][j] = (f32x4){0.f, 0.f, 0.f, 0.f};

#pragma unroll 1
  for (int kb = 0; kb < 24; ++kb) {
    const int dw = kb >> 3, cb = kb & 7;
    f16x8 bf[3];
#pragma unroll
    for (int j = 0; j < 3; ++j) {
      const int pos = py * 48 + j * 16 + l16;
      const float* p = src + ((size_t)b * 98 + (pos + dw)) * 256 + cb * 32 + quad * 8;
      const float4 x0 = *(const float4*)p;
      const float4 x1 = *(const float4*)(p + 4);
      f16x8 v;
      v[0] = (_Float16)x0.x; v[1] = (_Float16)x0.y; v[2] = (_Float16)x0.z; v[3] = (_Float16)x0.w;
      v[4] = (_Float16)x1.x; v[5] = (_Float16)x1.y; v[6] = (_Float16)x1.z; v[7] = (_Float16)x1.w;
      bf[j] = v;
    }
    f16x8 af[4];
#pragma unroll
    for (int i = 0; i < 4; ++i)
      af[i] = *(const f16x8*)(A0 + (size_t)(kb * 16 + wv * 4 + i) * 512 + l16 * 32 + quad * 8);
#pragma unroll
    for (int i = 0; i < 4; ++i)
#pragma unroll
      for (int j = 0; j < 3; ++j)
        acc[i][j] = __builtin_amdgcn_mfma_f32_16x16x32_f16(af[i], bf[j], acc[i][j], 0, 0, 0);
  }
#pragma unroll
  for (int i = 0; i < 4; ++i)
#pragma unroll
    for (int j = 0; j < 3; ++j) {
      const int pos = py * 48 + j * 16 + l16;
      const int co = wv * 64 + i * 16 + quad * 4;
      *(f32x4*)(dst + ((size_t)(cs * 8 + b) * 96 + pos) * 256 + co) = acc[i][j];
    }
}

// ---------------- c1 epilogue: tmp + U' + V', relu -> r_pad NHWC f16 ------
__global__ __launch_bounds__(256, 8) void k_epi_c1(
    const _Float16* __restrict__ tmp,
    const float* __restrict__ u2, const float* __restrict__ v2,
    _Float16* __restrict__ rpad)
{
  const int gid = blockIdx.x;                    // 0..767
  const int b = gid / 96, h = gid - b * 96;
  const int hcase = (h == 0) ? 0 : ((h == 95) ? 2 : 1);
  const size_t tbase = (size_t)(b * 96 + h) * 96 * 256;
#pragma unroll 1
  for (int it = 0; it < 12; ++it) {
    const int chunk = it * 256 + threadIdx.x;    // 0..3071
    const int w = chunk >> 5;
    const int co8 = (chunk & 31) * 8;
    const int wcase = (w == 0) ? 0 : ((w == 95) ? 2 : 1);
    const f16x8 t = *(const f16x8*)(tmp + tbase + (size_t)w * 256 + co8);
    const float* up = u2 + ((size_t)(hcase * 8 + b) * 96 + w) * 256 + co8;
    const float* vp = v2 + ((size_t)(wcase * 8 + b) * 96 + h) * 256 + co8;
    const float4 u0 = *(const float4*)up, u1 = *(const float4*)(up + 4);
    const float4 v0 = *(const float4*)vp, v1 = *(const float4*)(vp + 4);
    f16x8 r;
    r[0] = (_Float16)fmaxf((float)t[0] + u0.x + v0.x, 0.f);
    r[1] = (_Float16)fmaxf((float)t[1] + u0.y + v0.y, 0.f);
    r[2] = (_Float16)fmaxf((float)t[2] + u0.z + v0.z, 0.f);
    r[3] = (_Float16)fmaxf((float)t[3] + u0.w + v0.w, 0.f);
    r[4] = (_Float16)fmaxf((float)t[4] + u1.x + v1.x, 0.f);
    r[5] = (_Float16)fmaxf((float)t[5] + u1.y + v1.y, 0.f);
    r[6] = (_Float16)fmaxf((float)t[6] + u1.z + v1.z, 0.f);
    r[7] = (_Float16)fmaxf((float)t[7] + u1.w + v1.w, 0.f);
    *(f16x8*)(rpad + ((size_t)(b * HP + h + 1) * WP + w + 1) * 256 + co8) = r;
  }
}

// ---------------- final conv, relu, NCHW f32 to d_out ---------------------
__global__ __launch_bounds__(128, 2) void k_conv_c2(
    const _Float16* __restrict__ rpad, const _Float16* __restrict__ wkc2,
    const float* __restrict__ bias, float* __restrict__ dout)
{
  __shared__ __align__(16) char smem[SMEM_Q];
  const int lin = xcd_swz(blockIdx.x, 1152);
  const int spatial = lin >> 2, ch = lin & 3;
  CtxB c = make_ctxB<0>(spatial, ch);
  f32x4 acc[2][16];
  ZERO_ACCQ(acc)
  conv_accumB<0>(rpad, wkc2, smem, c, acc);

  const int w = c.w0 + c.wl;
#pragma unroll
  for (int j = 0; j < 16; ++j) {
    const int h = c.h0 + j;
    float* op = dout + (size_t)c.b * 2359296 + h * 96 + w;
#pragma unroll
    for (int i = 0; i < 2; ++i) {
      const int co = (ch * 4 + c.wv * 2 + i) * 16 + c.quad * 4;
      const float4 bs = *(const float4*)(bias + co);
      op[(size_t)(co + 0) * 9216] = fmaxf(acc[i][j][0] + bs.x, 0.f);
      op[(size_t)(co + 1) * 9216] = fmaxf(acc[i][j][1] + bs.y, 0.f);
      op[(size_t)(co + 2) * 9216] = fmaxf(acc[i][j][2] + bs.z, 0.f);
      op[(size_t)(co + 3) * 9216] = fmaxf(acc[i][j][3] + bs.w, 0.f);
    }
  }
}

// ---------------- aux kernels ---------------------------------------------
// Zero the 1-px halo ring of x_pad (z=0) and r_pad (z=1). 388 border pos/img.
__global__ void k_border(_Float16* __restrict__ xpad, _Float16* __restrict__ rpad)
{
  const int idx = blockIdx.x, b = blockIdx.y;
  _Float16* buf = blockIdx.z ? rpad : xpad;
  int h, w;
  if (idx < 98)       { h = 0;  w = idx; }
  else if (idx < 196) { h = 97; w = idx - 98; }
  else { const int r = idx - 196; h = 1 + (r >> 1); w = (r & 1) ? 97 : 0; }
  buf[((size_t)(b * HP + h) * WP + w) * 256 + threadIdx.x] = (_Float16)0.f;
}

__global__ void k_pack_x(const float* __restrict__ x, _Float16* __restrict__ xpad)
{
  __shared__ float tile[32][33];
  const int bh = blockIdx.x;
  const int b = bh / 96, h = bh - b * 96;
  const int c0 = blockIdx.y * 32, w0 = blockIdx.z * 32;
  const int tx = threadIdx.x & 31, ty = threadIdx.x >> 5;
#pragma unroll
  for (int i = 0; i < 4; ++i) {
    int cI = c0 + ty + i * 8;
    tile[ty + i * 8][tx] = x[(((size_t)b * 256 + cI) * 96 + h) * 96 + w0 + tx];
  }
  __syncthreads();
#pragma unroll
  for (int i = 0; i < 4; ++i) {
    int w = w0 + ty + i * 8;
    xpad[((size_t)(b * HP + h + 1) * WP + (w + 1)) * 256 + c0 + tx] =
        (_Float16)tile[tx][ty + i * 8];
  }
}

// main conv weights -> tiled layout: idx = ((cb*9+tap)*16 + cog)*512 + m*32 + kk
__global__ void k_repack_w(const float* w0, const float* g0, const float* w1, const float* g1,
                           const float* w2, const float* g2, const float* w3, const float* g3,
                           const float* w4, const float* g4, _Float16* __restrict__ wk)
{
  const int set = blockIdx.y;
  const float* w; const float* g;
  switch (set) {
    case 0: w = w0; g = g0; break;
    case 1: w = w1; g = g1; break;
    case 2: w = w2; g = g2; break;
    case 3: w = w3; g = g3; break;
    default: w = w4; g = g4; break;
  }
  const int t = blockIdx.x * 256 + threadIdx.x;   // co*256 + ci
  const int co = t >> 8, ci = t & 255;
  const int cb = ci >> 5, kk = ci & 31, cog = co >> 4, m = co & 15;
  const float gv = g[co];
  const float* src = w + ((size_t)co * 256 + ci) * 9;
  _Float16* dst = wk + (size_t)set * WSET + cog * 512 + m * 32 + kk;
#pragma unroll
  for (int tap = 0; tap < 9; ++tap)
    dst[(cb * 9 + tap) * 8192] = (_Float16)(src[tap] * gv);
}

// case-summed 1D weights for U'/V'
__global__ void k_repack_uvw(const float* __restrict__ wp, const float* __restrict__ gp,
                             _Float16* __restrict__ wuv)
{
  const int tcs = blockIdx.y;                             // 0..5 = t*3+cs
  const int tt = tcs / 3, cs = tcs - tt * 3;
  const int idx = blockIdx.x * 256 + threadIdx.x;         // co*256 + ci
  const int co = idx >> 8, ci = idx & 255;
  const float gv = gp[co];
  const float* src = wp + ((size_t)co * 256 + ci) * 9;    // [dh][dw]
  const int lo = (cs == 0) ? 1 : 0, hi = (cs == 2) ? 1 : 2;
  _Float16* base = wuv + (size_t)tcs * WUV_SET;
#pragma unroll
  for (int d = 0; d < 3; ++d) {
    float s = 0.f;
    for (int e = lo; e <= hi; ++e)
      s += (tt == 0) ? src[e * 3 + d] : src[d * 3 + e];
    const int k = d * 256 + ci;
    const int kb = k >> 5, kk = k & 31;
    base[(size_t)(kb * 16 + (co >> 4)) * 512 + (co & 15) * 32 + kk] = (_Float16)(s * gv);
  }
}

// ---------------- launcher -------------------------------------------------
extern "C" void kernel_launch(void* const* d_in, const int* in_sizes, int n_in,
                              void* d_out, int out_size, void* d_ws, size_t ws_size,
                              hipStream_t stream)
{
  const float* x    = (const float*)d_in[0];
  const float* w_p1 = (const float*)d_in[1];
  const float* g_p1 = (const float*)d_in[2];
  const float* b_p1 = (const float*)d_in[3];
  const float* w_p2 = (const float*)d_in[4];
  const float* g_p2 = (const float*)d_in[5];
  const float* b_p2 = (const float*)d_in[6];
  const float* w_p  = (const float*)d_in[7];
  const float* g_p  = (const float*)d_in[8];
  const float* b_p  = (const float*)d_in[9];
  const float* w_c1 = (const float*)d_in[10];
  const float* g_c1 = (const float*)d_in[11];
  const float* b_c1 = (const float*)d_in[12];
  const float* w_c2 = (const float*)d_in[13];
  const float* g_c2 = (const float*)d_in[14];
  const float* b_c2 = (const float*)d_in[15];

  char* ws = (char*)d_ws;
  size_t off = 0;
  _Float16* x_pad = (_Float16*)(ws + off); off += XPAD_E * 2;
  _Float16* r_pad = (_Float16*)(ws + off); off += XPAD_E * 2;
  _Float16* wks   = (_Float16*)(ws + off); off += (size_t)5 * WSET * 2;
  _Float16* wuv   = (_Float16*)(ws + off); off += (size_t)6 * WUV_SET * 2;
  float*    u_pad = (float*)(ws + off);    off += UVP_E * 4;
  float*    v_pad = (float*)(ws + off);    off += UVP_E * 4;
  float*    u2    = (float*)(ws + off);    off += UV2_E * 4;
  float*    v2    = (float*)(ws + off);    off += UV2_E * 4;
  _Float16* tmp   = (_Float16*)d_out;      // c1 conv scratch; free until c2
  (void)ws_size; (void)in_sizes; (void)n_in; (void)out_size;

  hipMemsetAsync(u_pad, 0, UVP_E * 4, stream);     // atomicMax targets + zero pad
  hipMemsetAsync(v_pad, 0, UVP_E * 4, stream);

  k_border    <<<dim3(388, 8, 2), 256, 0, stream>>>(x_pad, r_pad);
  k_pack_x    <<<dim3(768, 8, 3), 256, 0, stream>>>(x, x_pad);
  k_repack_w  <<<dim3(256, 5),    256, 0, stream>>>(w_p1, g_p1, w_p2, g_p2, w_p, g_p,
                                                    w_c1, g_c1, w_c2, g_c2, wks);
  k_repack_uvw<<<dim3(256, 6),    256, 0, stream>>>(w_p, g_p, wuv);
  k_conv_main <<<1728, 256, 0, stream>>>(x_pad, wks, b_p1, b_p2, b_p, b_c1,
                                         u_pad, v_pad, tmp);
  k_uv1d      <<<dim3(48, 2), 256, 0, stream>>>(u_pad, v_pad, wuv, u2, v2);
  k_epi_c1    <<<768, 256, 0, stream>>>(tmp, u2, v2, r_pad);
  k_conv_c2   <<<1152, 128, 0, stream>>>(r_pad, wks + (size_t)4 * WSET, b_c2,
                                         (float*)d_out);
}

// Round 10
// 515.659 us; speedup vs baseline: 1.4119x; 1.0223x over previous
//
#include <hip/hip_runtime.h>

// ct_layer round 17: consolidation — exact R14 (522us best) + epi XCD swizzle.
//   R15/R16 post-mortem: DPP o-shift attacked LDS reads, but with the correct
//   per-SIMD MFMA cost (19.4 cyc) neither LDS (43 B/cyc of 128) nor weight-L2
//   (12.9 of 56) binds; the 42% MFMA-idle gap is the 2-phase stage->barrier->
//   compute structure (af global loads share the in-order vmcnt queue with
//   global_load_lds, so counted-vmcnt pipelining is unsound here). Both DPP
//   variants regressed; reverted.

typedef _Float16 f16x8 __attribute__((ext_vector_type(8)));
typedef _Float16 f16x4v __attribute__((ext_vector_type(4)));
typedef float f32x4 __attribute__((ext_vector_type(4)));

#define HP 98
#define WP 98
#define KTOT 2304
#define WSET (256*KTOT)                // 589824 elems per weight set
#define XPAD_E ((size_t)8*HP*WP*256)
#define UVP_E  ((size_t)8*98*256)      // u_pad/v_pad f32 (atomic targets)
#define UV2_E  ((size_t)3*8*96*256)    // u2/v2 f32 [case][b][pos][co]
#define WUV_SET 196608                 // 256co * 768k per (t,case)

// XCD-aware block swizzle (requires nwg % 8 == 0).
__device__ __forceinline__ int xcd_swz(int bid, int nwg)
{
  return (bid & 7) * (nwg >> 3) + (bid >> 3);
}

// ---------------- Q16 conv core (4-wave): 32co x 256n per wave ------------
// Block = 4 waves x (2 cogs each) = 128 co x 256 n (16h x 16w tile).
// Halo 18x18 = 324 pos staged as 384 slots (24 KB), double-buffered.
// SW=0: halo h-major (lane=w, j=h); SW=1: w-major (lane=h, j=w).
#define BUF_Q 24576
#define SMEM_Q 49152

struct CtxQ {
  unsigned goff[6];
  unsigned lds_stage;
  unsigned aoff;
  int wl, quad, wv;
  int b, h0, w0;
};

template<int SW>
__device__ __forceinline__ CtxQ make_ctxQ(int spatial, int ch)
{
  CtxQ c;
  c.b = spatial / 36;
  const int tt = spatial - c.b * 36;
  const int ht = tt / 6, wt = tt - ht * 6;
  c.h0 = ht * 16; c.w0 = wt * 16;
  const int tid = threadIdx.x, lane = tid & 63;
  c.wv = tid >> 6;
  c.quad = lane >> 4; c.wl = lane & 15;
  c.aoff = (unsigned)((ch * 8 + c.wv * 2) * 512 + c.wl * 32 + c.quad * 8);
  const unsigned base_hw = (unsigned)(c.b * HP + c.h0) * WP + c.w0;
#pragma unroll
  for (int t = 0; t < 6; ++t) {
    int s = (c.wv * 6 + t) * 16 + (lane >> 2);   // 0..383; 324..383 dummy
    if (s > 323) s = 323;
    const int x = s / 18, y = s - x * 18;
    const int wh = SW ? y : x, ww = SW ? x : y;
    c.goff[t] = (base_hw + (unsigned)(wh * WP + ww)) * 256u + (lane & 3) * 8u;
  }
  c.lds_stage = (unsigned)(c.wv * 6) * 1024u + (unsigned)lane * 16u;
  return c;
}

__device__ __forceinline__ void stage_cbQ(const _Float16* __restrict__ src,
                                          char* sbuf, const CtxQ& c, int buf, int cb)
{
  char* l0 = sbuf + buf * BUF_Q + c.lds_stage;
#pragma unroll
  for (int t = 0; t < 6; ++t) {
    const _Float16* g = src + c.goff[t] + cb * 32;
    __builtin_amdgcn_global_load_lds(
        (const __attribute__((address_space(1))) void*)g,
        (__attribute__((address_space(3))) void*)(l0 + t * 1024), 16, 0, 0);
  }
}

// S: tap = (S==0) ? p*3+o : o*3+p  (weight layout tap = dh*3+dw).
template<int S>
__device__ __forceinline__ void conv_cb_plain(const _Float16* __restrict__ B,
                                              const _Float16* __restrict__ A,
                                              int wl, int quad, f32x4 acc[2][16])
{
#pragma unroll
  for (int o = 0; o < 3; ++o) {
    f16x8 af[3][2];
#pragma unroll
    for (int p = 0; p < 3; ++p) {
      const int tap = (S == 0) ? p * 3 + o : o * 3 + p;
#pragma unroll
      for (int i = 0; i < 2; ++i)
        af[p][i] = *(const f16x8*)(A + tap * 8192 + i * 512);
    }
#pragma unroll
    for (int jh = 0; jh < 2; ++jh) {
      f16x8 cache[10];
#pragma unroll
      for (int r = 0; r < 10; ++r)
        cache[r] = *(const f16x8*)(B + ((jh * 8 + r) * 18 + wl + o) * 32 + quad * 8);
#pragma unroll
      for (int p = 0; p < 3; ++p)
#pragma unroll
        for (int i = 0; i < 2; ++i)
#pragma unroll
          for (int j = 0; j < 8; ++j)
            acc[i][jh * 8 + j] = __builtin_amdgcn_mfma_f32_16x16x32_f16(
                af[p][i], cache[j + p], acc[i][jh * 8 + j], 0, 0, 0);
    }
  }
}

template<int S>
__device__ __forceinline__ void conv_accumQ(const _Float16* __restrict__ src,
                                            const _Float16* __restrict__ wkb,
                                            char* sbuf, const CtxQ& c, f32x4 acc[2][16])
{
  const _Float16* A0 = wkb + c.aoff;
  stage_cbQ(src, sbuf, c, 0, 0);
#pragma unroll 1
  for (int cb = 0; cb < 8; ++cb) {
    __syncthreads();
    if (cb < 7) stage_cbQ(src, sbuf, c, (cb + 1) & 1, cb + 1);
    conv_cb_plain<S>((const _Float16*)(sbuf + (cb & 1) * BUF_Q),
                     A0 + cb * (9 * 8192), c.wl, c.quad, acc);
  }
  __syncthreads();
}

#define ZERO_ACCQ(acc) \
  _Pragma("unroll") for (int i = 0; i < 2; ++i) \
  _Pragma("unroll") for (int j = 0; j < 16; ++j) acc[i][j] = (f32x4){0.f,0.f,0.f,0.f};

// ---------------- Q16b conv core (2-wave, for c2): 64co x 256n per block --
struct CtxB {
  unsigned goff[6];
  unsigned mask;                       // bits 0-5: y>=12 (delta sel); 6-11: dummy
  unsigned lds_stage;
  unsigned aoff;
  int wl, quad, wv;
  int b, h0, w0;
};

template<int SW>
__device__ __forceinline__ CtxB make_ctxB(int spatial, int ch)
{
  CtxB c;
  c.b = spatial / 36;
  const int tt = spatial - c.b * 36;
  const int ht = tt / 6, wt = tt - ht * 6;
  c.h0 = ht * 16; c.w0 = wt * 16;
  const int tid = threadIdx.x, lane = tid & 63;
  c.wv = tid >> 6;                     // 0..1
  c.quad = lane >> 4; c.wl = lane & 15;
  c.aoff = (unsigned)((ch * 4 + c.wv * 2) * 512 + c.wl * 32 + c.quad * 8);
  const unsigned base_hw = (unsigned)(c.b * HP + c.h0) * WP + c.w0;
  const int lg = lane >> 2;            // 0..15 slot-in-group
  c.mask = 0;
#pragma unroll
  for (int t = 0; t < 6; ++t) {
    const int s = (c.wv * 12 + t) * 16 + lg;   // <= 287, no clamp needed
    const int x = s / 18, y = s - x * 18;
    const int wh = SW ? y : x, ww = SW ? x : y;
    c.goff[t] = (base_hw + (unsigned)(wh * WP + ww)) * 256u + (lane & 3) * 8u;
    if (y >= 12) c.mask |= (1u << t);
    if (s > 227) c.mask |= (1u << (6 + t));    // s+96 > 323 -> dummy slot
  }
  c.lds_stage = (unsigned)(c.wv * 12) * 1024u + (unsigned)lane * 16u;
  return c;
}

template<int SW>
__device__ __forceinline__ void stage_cbB(const _Float16* __restrict__ src,
                                          char* sbuf, const CtxB& c, int buf, int cb)
{
  constexpr int D0 = SW ? (6 * WP + 5) * 256 : (5 * WP + 6) * 256;
  constexpr int D1 = SW ? (6 - 12 * WP) * 256 : (6 * WP - 12) * 256;
  char* l0 = sbuf + buf * BUF_Q + c.lds_stage;
#pragma unroll
  for (int t = 0; t < 6; ++t) {
    const _Float16* g = src + c.goff[t] + cb * 32;
    __builtin_amdgcn_global_load_lds(
        (const __attribute__((address_space(1))) void*)g,
        (__attribute__((address_space(3))) void*)(l0 + t * 1024), 16, 0, 0);
  }
#pragma unroll
  for (int t = 0; t < 6; ++t) {
    const int d = ((c.mask >> (6 + t)) & 1) ? 0
                : (((c.mask >> t) & 1) ? D1 : D0);
    const _Float16* g = src + (int)(c.goff[t] + (unsigned)d) + cb * 32;
    __builtin_amdgcn_global_load_lds(
        (const __attribute__((address_space(1))) void*)g,
        (__attribute__((address_space(3))) void*)(l0 + (6 + t) * 1024), 16, 0, 0);
  }
}

template<int S>
__device__ __forceinline__ void conv_accumB(const _Float16* __restrict__ src,
                                            const _Float16* __restrict__ wkb,
                                            char* sbuf, const CtxB& c, f32x4 acc[2][16])
{
  const _Float16* A0 = wkb + c.aoff;
  stage_cbB<S>(src, sbuf, c, 0, 0);
#pragma unroll 1
  for (int cb = 0; cb < 8; ++cb) {
    __syncthreads();
    if (cb < 7) stage_cbB<S>(src, sbuf, c, (cb + 1) & 1, cb + 1);
    conv_cb_plain<S>((const _Float16*)(sbuf + (cb & 1) * BUF_Q),
                     A0 + cb * (9 * 8192), c.wl, c.quad, acc);
  }
  __syncthreads();
}

// ---------------- merged main conv: p12 (1152 items) + c1conv (576) -------
__global__ __launch_bounds__(256, 2) void k_conv_main(
    const _Float16* __restrict__ xpad, const _Float16* __restrict__ wk,
    const float* __restrict__ bias1, const float* __restrict__ bias2,
    const float* __restrict__ bias_p, const float* __restrict__ bias_c1,
    float* __restrict__ u_pad, float* __restrict__ v_pad,
    _Float16* __restrict__ tmp)
{
  __shared__ __align__(16) char smem[SMEM_Q];
  const int lin = xcd_swz(blockIdx.x, 1728);
  f32x4 acc[2][16];
  ZERO_ACCQ(acc)
  if (lin < 1152) {
    const int set = lin >= 576;
    const int rem = lin - set * 576;
    const int spatial = rem >> 1, ch = rem & 1;
    if (set == 0) {
      CtxQ c = make_ctxQ<0>(spatial, ch);
      conv_accumQ<0>(xpad, wk, smem, c, acc);
#pragma unroll
      for (int i = 0; i < 2; ++i) {
        const int co = (ch * 8 + c.wv * 2 + i) * 16 + c.quad * 4;
        const float4 bs = *(const float4*)(bias1 + co);
        float m0 = 0.f, m1 = 0.f, m2 = 0.f, m3 = 0.f;
#pragma unroll
        for (int j = 0; j < 16; ++j) {             // j = h: in-lane max over h
          m0 = fmaxf(m0, acc[i][j][0] + bs.x);
          m1 = fmaxf(m1, acc[i][j][1] + bs.y);
          m2 = fmaxf(m2, acc[i][j][2] + bs.z);
          m3 = fmaxf(m3, acc[i][j][3] + bs.w);
        }
        unsigned* tgt = (unsigned*)(u_pad + ((size_t)c.b * 98 + (c.w0 + c.wl + 1)) * 256 + co);
        atomicMax(tgt + 0, __float_as_uint(m0));
        atomicMax(tgt + 1, __float_as_uint(m1));
        atomicMax(tgt + 2, __float_as_uint(m2));
        atomicMax(tgt + 3, __float_as_uint(m3));
      }
    } else {
      CtxQ c = make_ctxQ<1>(spatial, ch);
      conv_accumQ<1>(xpad, wk + WSET, smem, c, acc);
#pragma unroll
      for (int i = 0; i < 2; ++i) {
        const int co = (ch * 8 + c.wv * 2 + i) * 16 + c.quad * 4;
        const float4 bs = *(const float4*)(bias2 + co);
        float m0 = 0.f, m1 = 0.f, m2 = 0.f, m3 = 0.f;
#pragma unroll
        for (int j = 0; j < 16; ++j) {             // j = w: in-lane max over w
          m0 = fmaxf(m0, acc[i][j][0] + bs.x);
          m1 = fmaxf(m1, acc[i][j][1] + bs.y);
          m2 = fmaxf(m2, acc[i][j][2] + bs.z);
          m3 = fmaxf(m3, acc[i][j][3] + bs.w);
        }
        unsigned* tgt = (unsigned*)(v_pad + ((size_t)c.b * 98 + (c.h0 + c.wl + 1)) * 256 + co);
        atomicMax(tgt + 0, __float_as_uint(m0));
        atomicMax(tgt + 1, __float_as_uint(m1));
        atomicMax(tgt + 2, __float_as_uint(m2));
        atomicMax(tgt + 3, __float_as_uint(m3));
      }
    }
  } else {
    const int idx = lin - 1152;
    const int spatial = idx >> 1, ch = idx & 1;
    CtxQ c = make_ctxQ<0>(spatial, ch);
    conv_accumQ<0>(xpad, wk + (size_t)3 * WSET, smem, c, acc);
    const int w = c.w0 + c.wl;
#pragma unroll
    for (int i = 0; i < 2; ++i) {
      const int co = (ch * 8 + c.wv * 2 + i) * 16 + c.quad * 4;
      float4 bs = *(const float4*)(bias_p + co);
      const float4 b2 = *(const float4*)(bias_c1 + co);
      bs.x += b2.x; bs.y += b2.y; bs.z += b2.z; bs.w += b2.w;
#pragma unroll
      for (int j = 0; j < 16; ++j) {
        const int h = c.h0 + j;
        f16x4v pk;
        pk[0] = (_Float16)(acc[i][j][0] + bs.x);
        pk[1] = (_Float16)(acc[i][j][1] + bs.y);
        pk[2] = (_Float16)(acc[i][j][2] + bs.z);
        pk[3] = (_Float16)(acc[i][j][3] + bs.w);
        *(f16x4v*)(tmp + ((size_t)(c.b * 96 + h) * 96 + w) * 256 + co) = pk;
      }
    }
  }
}

// ---------------- 1D convs of u,v with case-summed weights ----------------
__global__ __launch_bounds__(256, 2) void k_uv1d(
    const float* __restrict__ u_pad, const float* __restrict__ v_pad,
    const _Float16* __restrict__ wuv, float* __restrict__ u2, float* __restrict__ v2)
{
  const int id = blockIdx.x;
  const int py = blockIdx.y;                     // 0..1 pos half
  const int b = id & 7, cs = (id >> 3) % 3, t = id / 24;
  const float* src = t ? v_pad : u_pad;
  float* dst = t ? v2 : u2;
  const _Float16* A0 = wuv + (size_t)(t * 3 + cs) * WUV_SET;
  const int lane = threadIdx.x & 63, wv = threadIdx.x >> 6;
  const int quad = lane >> 4, l16 = lane & 15;

  f32x4 acc[4][3];
#pragma unroll
  for (int i = 0; i < 4; ++i)
#pragma unroll
    for (int j = 0; j < 3; ++j) acc[i][j] = (f32x4){0.f, 0.f, 0.f, 0.f};

#pragma unroll 1
  for (int kb = 0; kb < 24; ++kb) {
    const int dw = kb >> 3, cb = kb & 7;
    f16x8 bf[3];
#pragma unroll
    for (int j = 0; j < 3; ++j) {
      const int pos = py * 48 + j * 16 + l16;
      const float* p = src + ((size_t)b * 98 + (pos + dw)) * 256 + cb * 32 + quad * 8;
      const float4 x0 = *(const float4*)p;
      const float4 x1 = *(const float4*)(p + 4);
      f16x8 v;
      v[0] = (_Float16)x0.x; v[1] = (_Float16)x0.y; v[2] = (_Float16)x0.z; v[3] = (_Float16)x0.w;
      v[4] = (_Float16)x1.x; v[5] = (_Float16)x1.y; v[6] = (_Float16)x1.z; v[7] = (_Float16)x1.w;
      bf[j] = v;
    }
    f16x8 af[4];
#pragma unroll
    for (int i = 0; i < 4; ++i)
      af[i] = *(const f16x8*)(A0 + (size_t)(kb * 16 + wv * 4 + i) * 512 + l16 * 32 + quad * 8);
#pragma unroll
    for (int i = 0; i < 4; ++i)
#pragma unroll
      for (int j = 0; j < 3; ++j)
        acc[i][j] = __builtin_amdgcn_mfma_f32_16x16x32_f16(af[i], bf[j], acc[i][j], 0, 0, 0);
  }
#pragma unroll
  for (int i = 0; i < 4; ++i)
#pragma unroll
    for (int j = 0; j < 3; ++j) {
      const int pos = py * 48 + j * 16 + l16;
      const int co = wv * 64 + i * 16 + quad * 4;
      *(f32x4*)(dst + ((size_t)(cs * 8 + b) * 96 + pos) * 256 + co) = acc[i][j];
    }
}

// ---------------- c1 epilogue: tmp + U' + V', relu -> r_pad NHWC f16 ------
__global__ __launch_bounds__(256, 8) void k_epi_c1(
    const _Float16* __restrict__ tmp,
    const float* __restrict__ u2, const float* __restrict__ v2,
    _Float16* __restrict__ rpad)
{
  const int gid = xcd_swz(blockIdx.x, 768);      // 0..767
  const int b = gid / 96, h = gid - b * 96;
  const int hcase = (h == 0) ? 0 : ((h == 95) ? 2 : 1);
  const size_t tbase = (size_t)(b * 96 + h) * 96 * 256;
#pragma unroll 1
  for (int it = 0; it < 12; ++it) {
    const int chunk = it * 256 + threadIdx.x;    // 0..3071
    const int w = chunk >> 5;
    const int co8 = (chunk & 31) * 8;
    const int wcase = (w == 0) ? 0 : ((w == 95) ? 2 : 1);
    const f16x8 t = *(const f16x8*)(tmp + tbase + (size_t)w * 256 + co8);
    const float* up = u2 + ((size_t)(hcase * 8 + b) * 96 + w) * 256 + co8;
    const float* vp = v2 + ((size_t)(wcase * 8 + b) * 96 + h) * 256 + co8;
    const float4 u0 = *(const float4*)up, u1 = *(const float4*)(up + 4);
    const float4 v0 = *(const float4*)vp, v1 = *(const float4*)(vp + 4);
    f16x8 r;
    r[0] = (_Float16)fmaxf((float)t[0] + u0.x + v0.x, 0.f);
    r[1] = (_Float16)fmaxf((float)t[1] + u0.y + v0.y, 0.f);
    r[2] = (_Float16)fmaxf((float)t[2] + u0.z + v0.z, 0.f);
    r[3] = (_Float16)fmaxf((float)t[3] + u0.w + v0.w, 0.f);
    r[4] = (_Float16)fmaxf((float)t[4] + u1.x + v1.x, 0.f);
    r[5] = (_Float16)fmaxf((float)t[5] + u1.y + v1.y, 0.f);
    r[6] = (_Float16)fmaxf((float)t[6] + u1.z + v1.z, 0.f);
    r[7] = (_Float16)fmaxf((float)t[7] + u1.w + v1.w, 0.f);
    *(f16x8*)(rpad + ((size_t)(b * HP + h + 1) * WP + w + 1) * 256 + co8) = r;
  }
}

// ---------------- final conv, relu, NCHW f32 to d_out ---------------------
__global__ __launch_bounds__(128, 2) void k_conv_c2(
    const _Float16* __restrict__ rpad, const _Float16* __restrict__ wkc2,
    const float* __restrict__ bias, float* __restrict__ dout)
{
  __shared__ __align__(16) char smem[SMEM_Q];
  const int lin = xcd_swz(blockIdx.x, 1152);
  const int spatial = lin >> 2, ch = lin & 3;
  CtxB c = make_ctxB<0>(spatial, ch);
  f32x4 acc[2][16];
  ZERO_ACCQ(acc)
  conv_accumB<0>(rpad, wkc2, smem, c, acc);

  const int w = c.w0 + c.wl;
#pragma unroll
  for (int j = 0; j < 16; ++j) {
    const int h = c.h0 + j;
    float* op = dout + (size_t)c.b * 2359296 + h * 96 + w;
#pragma unroll
    for (int i = 0; i < 2; ++i) {
      const int co = (ch * 4 + c.wv * 2 + i) * 16 + c.quad * 4;
      const float4 bs = *(const float4*)(bias + co);
      op[(size_t)(co + 0) * 9216] = fmaxf(acc[i][j][0] + bs.x, 0.f);
      op[(size_t)(co + 1) * 9216] = fmaxf(acc[i][j][1] + bs.y, 0.f);
      op[(size_t)(co + 2) * 9216] = fmaxf(acc[i][j][2] + bs.z, 0.f);
      op[(size_t)(co + 3) * 9216] = fmaxf(acc[i][j][3] + bs.w, 0.f);
    }
  }
}

// ---------------- aux kernels ---------------------------------------------
// Zero the 1-px halo ring of x_pad (z=0) and r_pad (z=1). 388 border pos/img.
__global__ void k_border(_Float16* __restrict__ xpad, _Float16* __restrict__ rpad)
{
  const int idx = blockIdx.x, b = blockIdx.y;
  _Float16* buf = blockIdx.z ? rpad : xpad;
  int h, w;
  if (idx < 98)       { h = 0;  w = idx; }
  else if (idx < 196) { h = 97; w = idx - 98; }
  else { const int r = idx - 196; h = 1 + (r >> 1); w = (r & 1) ? 97 : 0; }
  buf[((size_t)(b * HP + h) * WP + w) * 256 + threadIdx.x] = (_Float16)0.f;
}

__global__ void k_pack_x(const float* __restrict__ x, _Float16* __restrict__ xpad)
{
  __shared__ float tile[32][33];
  const int bh = blockIdx.x;
  const int b = bh / 96, h = bh - b * 96;
  const int c0 = blockIdx.y * 32, w0 = blockIdx.z * 32;
  const int tx = threadIdx.x & 31, ty = threadIdx.x >> 5;
#pragma unroll
  for (int i = 0; i < 4; ++i) {
    int cI = c0 + ty + i * 8;
    tile[ty + i * 8][tx] = x[(((size_t)b * 256 + cI) * 96 + h) * 96 + w0 + tx];
  }
  __syncthreads();
#pragma unroll
  for (int i = 0; i < 4; ++i) {
    int w = w0 + ty + i * 8;
    xpad[((size_t)(b * HP + h + 1) * WP + (w + 1)) * 256 + c0 + tx] =
        (_Float16)tile[tx][ty + i * 8];
  }
}

// main conv weights -> tiled layout: idx = ((cb*9+tap)*16 + cog)*512 + m*32 + kk
__global__ void k_repack_w(const float* w0, const float* g0, const float* w1, const float* g1,
                           const float* w2, const float* g2, const float* w3, const float* g3,
                           const float* w4, const float* g4, _Float16* __restrict__ wk)
{
  const int set = blockIdx.y;
  const float* w; const float* g;
  switch (set) {
    case 0: w = w0; g = g0; break;
    case 1: w = w1; g = g1; break;
    case 2: w = w2; g = g2; break;
    case 3: w = w3; g = g3; break;
    default: w = w4; g = g4; break;
  }
  const int t = blockIdx.x * 256 + threadIdx.x;   // co*256 + ci
  const int co = t >> 8, ci = t & 255;
  const int cb = ci >> 5, kk = ci & 31, cog = co >> 4, m = co & 15;
  const float gv = g[co];
  const float* src = w + ((size_t)co * 256 + ci) * 9;
  _Float16* dst = wk + (size_t)set * WSET + cog * 512 + m * 32 + kk;
#pragma unroll
  for (int tap = 0; tap < 9; ++tap)
    dst[(cb * 9 + tap) * 8192] = (_Float16)(src[tap] * gv);
}

// case-summed 1D weights for U'/V'
__global__ void k_repack_uvw(const float* __restrict__ wp, const float* __restrict__ gp,
                             _Float16* __restrict__ wuv)
{
  const int tcs = blockIdx.y;                             // 0..5 = t*3+cs
  const int tt = tcs / 3, cs = tcs - tt * 3;
  const int idx = blockIdx.x * 256 + threadIdx.x;         // co*256 + ci
  const int co = idx >> 8, ci = idx & 255;
  const float gv = gp[co];
  const float* src = wp + ((size_t)co * 256 + ci) * 9;    // [dh][dw]
  const int lo = (cs == 0) ? 1 : 0, hi = (cs == 2) ? 1 : 2;
  _Float16* base = wuv + (size_t)tcs * WUV_SET;
#pragma unroll
  for (int d = 0; d < 3; ++d) {
    float s = 0.f;
    for (int e = lo; e <= hi; ++e)
      s += (tt == 0) ? src[e * 3 + d] : src[d * 3 + e];
    const int k = d * 256 + ci;
    const int kb = k >> 5, kk = k & 31;
    base[(size_t)(kb * 16 + (co >> 4)) * 512 + (co & 15) * 32 + kk] = (_Float16)(s * gv);
  }
}

// ---------------- launcher -------------------------------------------------
extern "C" void kernel_launch(void* const* d_in, const int* in_sizes, int n_in,
                              void* d_out, int out_size, void* d_ws, size_t ws_size,
                              hipStream_t stream)
{
  const float* x    = (const float*)d_in[0];
  const float* w_p1 = (const float*)d_in[1];
  const float* g_p1 = (const float*)d_in[2];
  const float* b_p1 = (const float*)d_in[3];
  const float* w_p2 = (const float*)d_in[4];
  const float* g_p2 = (const float*)d_in[5];
  const float* b_p2 = (const float*)d_in[6];
  const float* w_p  = (const float*)d_in[7];
  const float* g_p  = (const float*)d_in[8];
  const float* b_p  = (const float*)d_in[9];
  const float* w_c1 = (const float*)d_in[10];
  const float* g_c1 = (const float*)d_in[11];
  const float* b_c1 = (const float*)d_in[12];
  const float* w_c2 = (const float*)d_in[13];
  const float* g_c2 = (const float*)d_in[14];
  const float* b_c2 = (const float*)d_in[15];

  char* ws = (char*)d_ws;
  size_t off = 0;
  _Float16* x_pad = (_Float16*)(ws + off); off += XPAD_E * 2;
  _Float16* r_pad = (_Float16*)(ws + off); off += XPAD_E * 2;
  _Float16* wks   = (_Float16*)(ws + off); off += (size_t)5 * WSET * 2;
  _Float16* wuv   = (_Float16*)(ws + off); off += (size_t)6 * WUV_SET * 2;
  float*    u_pad = (float*)(ws + off);    off += UVP_E * 4;
  float*    v_pad = (float*)(ws + off);    off += UVP_E * 4;
  float*    u2    = (float*)(ws + off);    off += UV2_E * 4;
  float*    v2    = (float*)(ws + off);    off += UV2_E * 4;
  _Float16* tmp   = (_Float16*)d_out;      // c1 conv scratch; free until c2
  (void)ws_size; (void)in_sizes; (void)n_in; (void)out_size;

  hipMemsetAsync(u_pad, 0, UVP_E * 4, stream);     // atomicMax targets + zero pad
  hipMemsetAsync(v_pad, 0, UVP_E * 4, stream);

  k_border    <<<dim3(388, 8, 2), 256, 0, stream>>>(x_pad, r_pad);
  k_pack_x    <<<dim3(768, 8, 3), 256, 0, stream>>>(x, x_pad);
  k_repack_w  <<<dim3(256, 5),    256, 0, stream>>>(w_p1, g_p1, w_p2, g_p2, w_p, g_p,
                                                    w_c1, g_c1, w_c2, g_c2, wks);
  k_repack_uvw<<<dim3(256, 6),    256, 0, stream>>>(w_p, g_p, wuv);
  k_conv_main <<<1728, 256, 0, stream>>>(x_pad, wks, b_p1, b_p2, b_p, b_c1,
                                         u_pad, v_pad, tmp);
  k_uv1d      <<<dim3(48, 2), 256, 0, stream>>>(u_pad, v_pad, wuv, u2, v2);
  k_epi_c1    <<<768, 256, 0, stream>>>(tmp, u2, v2, r_pad);
  k_conv_c2   <<<1152, 128, 0, stream>>>(r_pad, wks + (size_t)4 * WSET, b_c2,
                                         (float*)d_out);
}